// Round 5
// baseline (532.127 us; speedup 1.0000x reference)
//
#include <hip/hip_runtime.h>
#include <stdint.h>
#include <math.h>

typedef __attribute__((ext_vector_type(4))) int i32x4;

#define GLD16(gp, lp)                                                     \
  __builtin_amdgcn_global_load_lds(                                       \
      (__attribute__((address_space(1))) void*)(gp),                      \
      (__attribute__((address_space(3))) void*)(lp), 16, 0, 0)

// ---------- merged prep (grid-stride): Wq[8192][4096]=[qwx|qwh] i8,
// Aq[1024][12288]=[d5|d4|d3|d2|d1|qx] i8.
// hx = d1*2^-4 + d2*2^-11 + d3*2^-18 + d4*2^-25 + d5*2^-32 (exact in fp32)
__global__ void __launch_bounds__(256) k_prep(
    const float* __restrict__ wx, const float* __restrict__ wh,
    const float* __restrict__ x, const float* __restrict__ hx,
    signed char* __restrict__ Wq, signed char* __restrict__ Aq) {
  const int NW = 8388608;            // Wq char4 units
  const int NT = NW + 524288;        // + Aq col4 units
  const int stride = gridDim.x * 256;
  for (int u = blockIdx.x * 256 + threadIdx.x; u < NT; u += stride) {
    if (u < NW) {
      int e = u << 2;
      int g = e >> 12;
      int c = e & 4095;
      const float* src = (c < 2048) ? (wx + g * 2048 + c)
                                    : (wh + g * 2048 + (c - 2048));
      float4 v = *(const float4*)src;
      char4 o;
      o.x = (signed char)(int)rintf(fminf(fmaxf(v.x * 127.f, -127.f), 127.f));
      o.y = (signed char)(int)rintf(fminf(fmaxf(v.y * 127.f, -127.f), 127.f));
      o.z = (signed char)(int)rintf(fminf(fmaxf(v.z * 127.f, -127.f), 127.f));
      o.w = (signed char)(int)rintf(fminf(fmaxf(v.w * 127.f, -127.f), 127.f));
      *(char4*)(Wq + e) = o;
    } else {
      int ua = u - NW;
      int e = ua << 2;
      int b = e >> 11;
      int c = e & 2047;
      float4 xv = *(const float4*)(x + b * 2048 + c);
      float4 hv = *(const float4*)(hx + b * 2048 + c);
      float xa[4] = {xv.x, xv.y, xv.z, xv.w};
      float ha[4] = {hv.x, hv.y, hv.z, hv.w};
      char4 q4, s1, s2, s3, s4, s5;
      signed char* qp = (signed char*)&q4;
      signed char* p1 = (signed char*)&s1;
      signed char* p2 = (signed char*)&s2;
      signed char* p3 = (signed char*)&s3;
      signed char* p4 = (signed char*)&s4;
      signed char* p5 = (signed char*)&s5;
      #pragma unroll
      for (int j = 0; j < 4; ++j) {
        qp[j] = (signed char)(int)rintf(fminf(fmaxf(xa[j] * 127.f, -127.f), 127.f));
        float r = ha[j];
        float d1 = rintf(r * 0x1p4f);    r -= d1 * 0x1p-4f;
        float d2 = rintf(r * 0x1p11f);   r -= d2 * 0x1p-11f;
        float d3 = rintf(r * 0x1p18f);   r -= d3 * 0x1p-18f;
        float d4 = rintf(r * 0x1p25f);   r -= d4 * 0x1p-25f;
        float d5 = rintf(r * 0x1p32f);
        p1[j] = (signed char)(int)d1;
        p2[j] = (signed char)(int)d2;
        p3[j] = (signed char)(int)d3;
        p4[j] = (signed char)(int)d4;
        p5[j] = (signed char)(int)d5;
      }
      size_t base = (size_t)b * 12288;
      *(char4*)(Aq + base + 0 * 2048 + c) = s5;
      *(char4*)(Aq + base + 1 * 2048 + c) = s4;
      *(char4*)(Aq + base + 2 * 2048 + c) = s3;
      *(char4*)(Aq + base + 3 * 2048 + c) = s2;
      *(char4*)(Aq + base + 4 * 2048 + c) = s1;
      *(char4*)(Aq + base + 5 * 2048 + c) = q4;
    }
  }
}

// ---------- fused exact i8 GEMM + LSTM, double-buffered pipeline ----------
// BM=128, BN=128 (4 gates x 32 j), BK=128. 4 waves 2x2, wave tile 64x64.
// 96 steps = 6 phases x 16 k-chunks. Per step: wait current chunk ->
// s_barrier -> issue next chunk (stays in flight across compute) ->
// 32 MFMA/wave. One i32 acc; fp64 D += w[ph]*acc per phase. LDS rows 128 B,
// 8-chunk XOR swizzle (pos = c ^ (row&7)): measured-conflict-free b128.
__global__ void __launch_bounds__(256, 2) k_gemm_lstm(
    const signed char* __restrict__ Aq, const signed char* __restrict__ Wq,
    const float* __restrict__ bx, const float* __restrict__ bh,
    const float* __restrict__ cx, float* __restrict__ out) {
  __shared__ __align__(16) signed char smem[65536];
  // A buffers at 0 / 16384; B buffers at 32768 / 49152

  const int t  = threadIdx.x;
  const int wv = t >> 6;
  const int ln = t & 63;
  const int wm = wv & 1;
  const int wn = wv >> 1;
  const int lr = ln & 15;
  const int q  = ln >> 4;

  const int j0 = blockIdx.x * 32;
  const int m0 = blockIdx.y * 128;

  // staging source bases: issue i, slot s=i*256+t; row r=s>>3 (128 rows of
  // 8 chunks), pos p=s&7 holds logical chunk c = p ^ (r&7)
  int sA[4], sB[4];
  #pragma unroll
  for (int i = 0; i < 4; ++i) {
    int s = i * 256 + t;
    int r = s >> 3;
    int c = (s & 7) ^ (r & 7);
    sA[i] = (m0 + r) * 12288 + c * 16;
    int wrow = (r >> 5) * 2048 + j0 + (r & 31);   // gate*2048 + j
    sB[i] = wrow * 4096 + c * 16;
  }
  const int ldst = wv * 1024;   // wave-uniform LDS offset within an issue block

  // LDS read row bases
  int arow[4], brow[4];
  #pragma unroll
  for (int f = 0; f < 4; ++f) {
    arow[f] = (wm * 64 + f * 16 + lr) * 128;
    brow[f] = 32768 + (wn * 64 + f * 16 + lr) * 128;
  }

  i32x4 acc[4][4];
  double D[4][4][4];
  #pragma unroll
  for (int mf = 0; mf < 4; ++mf)
    #pragma unroll
    for (int nf = 0; nf < 4; ++nf) {
      acc[mf][nf] = (i32x4){0, 0, 0, 0};
      #pragma unroll
      for (int r = 0; r < 4; ++r) D[mf][nf][r] = 0.0;
    }

  const double wph[6] = {0x1p-32 / 127.0, 0x1p-25 / 127.0, 0x1p-18 / 127.0,
                         0x1p-11 / 127.0, 0x1p-4 / 127.0, 1.0 / 16129.0};

  // prologue: stage step 0 (phase 0 = digit -> B colbase 2048) into buffer 0
  #pragma unroll
  for (int i = 0; i < 4; ++i) {
    GLD16(Aq + sA[i], smem + i * 4096 + ldst);
    GLD16(Wq + sB[i] + 2048, smem + 32768 + i * 4096 + ldst);
  }

  #pragma unroll 1
  for (int s = 0; s < 96; ++s) {
    const int p = s & 1;
    asm volatile("s_waitcnt vmcnt(0)" ::: "memory");
    asm volatile("s_barrier" ::: "memory");
    if (s < 95) {
      const int s1 = s + 1;
      const int aoffs = s1 * 128;                       // ph*2048 + kc*128
      const int boffs = ((s1 < 80) ? 2048 : 0) + ((s1 & 15) << 7);
      const int nb = (1 - p) * 16384;
      #pragma unroll
      for (int i = 0; i < 4; ++i) {
        GLD16(Aq + sA[i] + aoffs, smem + nb + i * 4096 + ldst);
        GLD16(Wq + sB[i] + boffs, smem + 32768 + nb + i * 4096 + ldst);
      }
    }
    const int cb = p * 16384;
    #pragma unroll
    for (int kst = 0; kst < 2; ++kst) {
      const int pos = ((kst * 4 + q) ^ (lr & 7)) * 16;
      i32x4 af[4], bf[4];
      #pragma unroll
      for (int mf = 0; mf < 4; ++mf)
        af[mf] = *(const i32x4*)&smem[cb + arow[mf] + pos];
      #pragma unroll
      for (int nf = 0; nf < 4; ++nf)
        bf[nf] = *(const i32x4*)&smem[cb + brow[nf] + pos];
      #pragma unroll
      for (int mf = 0; mf < 4; ++mf)
        #pragma unroll
        for (int nf = 0; nf < 4; ++nf)
          acc[mf][nf] = __builtin_amdgcn_mfma_i32_16x16x64_i8(
              af[mf], bf[nf], acc[mf][nf], 0, 0, 0);
    }
    if ((s & 15) == 15) {          // phase boundary: fold into fp64 D
      const double w = wph[s >> 4];
      #pragma unroll
      for (int mf = 0; mf < 4; ++mf)
        #pragma unroll
        for (int nf = 0; nf < 4; ++nf) {
          #pragma unroll
          for (int r = 0; r < 4; ++r)
            D[mf][nf][r] += w * (double)acc[mf][nf][r];
          acc[mf][nf] = (i32x4){0, 0, 0, 0};
        }
    }
  }

  // ---------------- epilogue ----------------
  float (*Lgo)[128][33] = (float(*)[128][33])smem;

  __syncthreads();
  if (wn == 1) {   // gates g (nf 0,1), o (nf 2,3): activate, stash q*127
    #pragma unroll
    for (int mf = 0; mf < 4; ++mf) {
      #pragma unroll
      for (int nf = 0; nf < 4; ++nf) {
        int gate = 2 + (nf >> 1);
        int jj = (nf & 1) * 16 + lr;
        int gcol = gate * 2048 + j0 + jj;
        double bsum = (double)bx[gcol] + (double)bh[gcol];
        #pragma unroll
        for (int r = 0; r < 4; ++r) {
          double pre = D[mf][nf][r] + bsum;
          double av = (gate == 2) ? tanh(pre) : (1.0 / (1.0 + exp(-pre)));
          double qv = rint(fmin(fmax(av * 127.0, -127.0), 127.0));
          int m = wm * 64 + mf * 16 + q * 4 + r;
          Lgo[gate - 2][m][jj] = (float)qv;
        }
      }
    }
  }
  __syncthreads();
  if (wn == 0) {   // gates f (nf 0,1), i (nf 2,3): combine + store
    #pragma unroll
    for (int mf = 0; mf < 4; ++mf) {
      #pragma unroll
      for (int nfp = 0; nfp < 2; ++nfp) {
        int jj = nfp * 16 + lr;
        int gcf = j0 + jj;
        int gci = 2048 + j0 + jj;
        double bf_ = (double)bx[gcf] + (double)bh[gcf];
        double bi_ = (double)bx[gci] + (double)bh[gci];
        #pragma unroll
        for (int r = 0; r < 4; ++r) {
          int m = wm * 64 + mf * 16 + q * 4 + r;
          double fpre = D[mf][nfp][r] + bf_;
          double ipre = D[mf][nfp + 2][r] + bi_;
          double fv = rint(fmin(fmax((1.0 / (1.0 + exp(-fpre))) * 127.0, -127.0), 127.0)) / 127.0;
          double iv = rint(fmin(fmax((1.0 / (1.0 + exp(-ipre))) * 127.0, -127.0), 127.0)) / 127.0;
          double gv = (double)Lgo[0][m][jj] / 127.0;
          double ov = (double)Lgo[1][m][jj] / 127.0;
          int row = m0 + m;
          int col = j0 + jj;
          double cn = fv * (double)cx[row * 2048 + col] + iv * gv;
          double tq = rint(fmin(fmax(tanh(cn) * 127.0, -127.0), 127.0)) / 127.0;
          double hv = ov * tq;
          double cq = rint(fmin(fmax(cn * 127.0, -127.0), 127.0)) / 127.0;
          out[row * 2048 + col] = (float)hv;
          out[2097152 + row * 2048 + col] = (float)cq;
        }
      }
    }
  }
}

// ---------- launch ----------
extern "C" void kernel_launch(void* const* d_in, const int* in_sizes, int n_in,
                              void* d_out, int out_size, void* d_ws, size_t ws_size,
                              hipStream_t stream) {
  const float* x  = (const float*)d_in[0];
  const float* hx = (const float*)d_in[1];
  const float* cx = (const float*)d_in[2];
  const float* wx = (const float*)d_in[3];
  const float* bx = (const float*)d_in[4];
  const float* wh = (const float*)d_in[5];
  const float* bh = (const float*)d_in[6];
  float* out = (float*)d_out;

  signed char* Wq = (signed char*)d_ws;               // 33,554,432 B
  signed char* Aq = (signed char*)d_ws + 33554432;    // 12,582,912 B

  k_prep<<<dim3(1024), dim3(256), 0, stream>>>(wx, wh, x, hx, Wq, Aq);
  k_gemm_lstm<<<dim3(64, 8), dim3(256), 0, stream>>>(Aq, Wq, bx, bh, cx, out);
}